// Round 13
// baseline (271.703 us; speedup 1.0000x reference)
//
#include <hip/hip_runtime.h>
#include <hip/hip_bf16.h>

#define L_ 256
#define H_ 4
#define ROWS 2048
#define NEGV (-4294967295.0f)   // -(2^32)+1 as float

typedef unsigned short us16;

__device__ __forceinline__ float us2f(us16 u){ return __uint_as_float(((unsigned)u)<<16); }
__device__ __forceinline__ us16 f2us(float f){ __hip_bfloat16 h=__float2bfloat16(f); return *(us16*)&h; }

struct KArgs {
    const int *log_seqs, *tmat, *pos_seqs, *neg_seqs;
    const float *item_emb, *posK, *posV, *timeK, *timeV;
    const float *ln1g, *ln1b, *bq, *bk, *bv, *ln2g, *ln2b, *b1, *b2, *lnfg, *lnfb;
    const float *Wq, *Wk, *Wv, *W1, *W2;
    float *qin0, *qin1, *out;
    us16 *wsWT, *tmK, *tmV, *Qb0, *Kb0, *Vb0, *Qb1, *Kb1, *Vb1;
};

// LayerNorm of 8 LDS rows in place; thread t: row t>>5, 4 elems strided 32.
__device__ __forceinline__ void ln_rows(float* sA,
        const float* __restrict__ g, const float* __restrict__ b,
        float* qin_out, int r0, int tid){
    int r=tid>>5, l=tid&31;
    float* x=sA+r*128;
    float x0=x[l],x1=x[l+32],x2=x[l+64],x3=x[l+96];
    float s=x0+x1+x2+x3;
    #pragma unroll
    for(int o=16;o;o>>=1) s+=__shfl_xor(s,o,64);
    float m=s*(1.f/128.f);
    float d0=x0-m,d1=x1-m,d2=x2-m,d3=x3-m;
    float v=d0*d0+d1*d1+d2*d2+d3*d3;
    #pragma unroll
    for(int o=16;o;o>>=1) v+=__shfl_xor(v,o,64);
    float rstd=rsqrtf(v*(1.f/128.f)+1e-8f);
    float y0=d0*rstd*g[l]+b[l];
    float y1=d1*rstd*g[l+32]+b[l+32];
    float y2=d2*rstd*g[l+64]+b[l+64];
    float y3=d3*rstd*g[l+96]+b[l+96];
    x[l]=y0; x[l+32]=y1; x[l+64]=y2; x[l+96]=y3;
    if(qin_out){
        float* q=qin_out+(size_t)(r0+r)*128;
        q[l]=y0; q[l+32]=y1; q[l+64]=y2; q[l+96]=y3;
    }
}

// 2-row x 2-col register tile over K=128 from LDS (k_pre only)
__device__ __forceinline__ void gemm2x2(const float* A, const us16* sW,
        int ra, int rb, int c0, float* acc){
    float a00=0,a01=0,a10=0,a11=0;
    const float* Ar=A+ra*128;
    const float* Br=A+rb*128;
    #pragma unroll 8
    for(int k=0;k<128;k++){
        ushort2 wp=*(const ushort2*)(sW+k*128+c0);
        float w0=us2f(wp.x), w1=us2f(wp.y);
        float x0=Ar[k], x1=Br[k];
        a00=fmaf(x0,w0,a00); a01=fmaf(x0,w1,a01);
        a10=fmaf(x1,w0,a10); a11=fmaf(x1,w1,a11);
    }
    acc[0]=a00; acc[1]=a01; acc[2]=a10; acc[3]=a11;
}

// dot of bf16 row (global, contiguous 128) with fp32 LDS row (wave-broadcast).
// unroll 4 -> max 4 uint4 loads in flight (~16 VGPRs) -- R10 spill lesson.
__device__ __forceinline__ float gemv_wt(const us16* __restrict__ wt, const float* x){
    float acc=0;
    const uint4* W4=(const uint4*)wt;
    #pragma unroll 4
    for(int c=0;c<16;c++){
        uint4 wv=W4[c];
        const us16* wu=(const us16*)&wv;
        const float* xx=x+c*8;
        acc += xx[0]*us2f(wu[0])+xx[1]*us2f(wu[1])+xx[2]*us2f(wu[2])+xx[3]*us2f(wu[3])
             + xx[4]*us2f(wu[4])+xx[5]*us2f(wu[5])+xx[6]*us2f(wu[6])+xx[7]*us2f(wu[7]);
    }
    return acc;
}

// k_pre: bid<768: embed+LN1+QKV(L0) (8 rows/block, fp32 weights staged->bf16 LDS).
//        bid 768..879: convert+TRANSPOSE 7 tail matrices fp32 -> bf16 wsWT.
//        bid 880..945: convert timeK/timeV tables to bf16.
__global__ __launch_bounds__(256) void k_pre(KArgs a){
    __shared__ __align__(16) char smem[36864];
    int tid=threadIdx.x, bid=blockIdx.x;
    if(bid<768){
        us16* sW=(us16*)smem;
        float* sA=(float*)(smem+32768);
        int m=bid>>8, rg=bid&255, r0=rg*8;
        {   // embed 8 rows
            int rl=tid>>5, c4=tid&31;
            int id=a.log_seqs[r0+rl];
            float4 v=((const float4*)a.item_emb)[id*32+c4];
            float sc = id? 11.3137085f : 0.f;   // sqrt(128), pad-zeroed
            v.x*=sc; v.y*=sc; v.z*=sc; v.w*=sc;
            ((float4*)sA)[tid]=v;
        }
        const float* Wsrc=(m==0)?a.Wq:(m==1)?a.Wk:a.Wv;
        {   // stage fp32 weights -> bf16 LDS
            const float4* src=(const float4*)Wsrc;
            ushort4* dst=(ushort4*)sW;
            #pragma unroll
            for(int j=0;j<16;j++){
                float4 w=src[j*256+tid];
                ushort4 o; o.x=f2us(w.x);o.y=f2us(w.y);o.z=f2us(w.z);o.w=f2us(w.w);
                dst[j*256+tid]=o;
            }
        }
        __syncthreads();
        if(m==0){ ln_rows(sA, a.ln1g, a.ln1b, a.qin0, r0, tid); __syncthreads(); }
        int cp=tid&63, rp=tid>>6, c0=2*cp, ra=2*rp, rb=ra+1;
        float acc[4];
        gemm2x2(sA,sW,ra,rb,c0,acc);
        if(m==0){
            float b0v=a.bq[c0], b1v=a.bq[c0+1];
            ushort2 s0; s0.x=f2us(acc[0]+b0v); s0.y=f2us(acc[1]+b1v);
            ushort2 s1; s1.x=f2us(acc[2]+b0v); s1.y=f2us(acc[3]+b1v);
            *(ushort2*)(a.Qb0+(size_t)(r0+ra)*128+c0)=s0;
            *(ushort2*)(a.Qb0+(size_t)(r0+rb)*128+c0)=s1;
        } else {
            const float* bb=(m==1)?a.bk:a.bv;
            const float* pp=(m==1)?a.posK:a.posV;
            us16* Oo=(m==1)?a.Kb0:a.Vb0;
            int qa=(r0+ra)&255, qb2=(r0+rb)&255;
            float b0v=bb[c0], b1v=bb[c0+1];
            ushort2 s0; s0.x=f2us(acc[0]+b0v+pp[qa*128+c0]);  s0.y=f2us(acc[1]+b1v+pp[qa*128+c0+1]);
            ushort2 s1; s1.x=f2us(acc[2]+b0v+pp[qb2*128+c0]); s1.y=f2us(acc[3]+b1v+pp[qb2*128+c0+1]);
            *(ushort2*)(Oo+(size_t)(r0+ra)*128+c0)=s0;
            *(ushort2*)(Oo+(size_t)(r0+rb)*128+c0)=s1;
        }
    } else if(bid<880){
        // transpose+convert: wsWT[m][c*128+k] = W[m][k*128+c]
        int j=bid-768; int m=j>>4; int idx=(j&15)*256+tid;   // float4 idx
        const float* base;
        switch(m){
            case 0: base=a.W1; break;        case 1: base=a.W2; break;
            case 2: base=a.Wq+16384; break;  case 3: base=a.Wk+16384; break;
            case 4: base=a.Wv+16384; break;  case 5: base=a.W1+16384; break;
            default: base=a.W2+16384; break;
        }
        float4 v=((const float4*)base)[idx];
        int kRow = idx>>5;            // source row
        int c0 = (idx&31)*4;          // source col base
        us16* dst = a.wsWT + (size_t)m*16384;
        dst[(size_t)(c0+0)*128 + kRow]=f2us(v.x);
        dst[(size_t)(c0+1)*128 + kRow]=f2us(v.y);
        dst[(size_t)(c0+2)*128 + kRow]=f2us(v.z);
        dst[(size_t)(c0+3)*128 + kRow]=f2us(v.w);
    } else {
        int gi=(bid-880)*256+tid;     // 2 x 8224 float4
        if(gi<8224){
            float4 v=((const float4*)a.timeK)[gi];
            ushort4 o; o.x=f2us(v.x);o.y=f2us(v.y);o.z=f2us(v.z);o.w=f2us(v.w);
            ((ushort4*)a.tmK)[gi]=o;
        } else if(gi<16448){
            int g2=gi-8224;
            float4 v=((const float4*)a.timeV)[g2];
            ushort4 o; o.x=f2us(v.x);o.y=f2us(v.y);o.z=f2us(v.z);o.w=f2us(v.w);
            ((ushort4*)a.tmV)[g2]=o;
        }
    }
}

// k_attn1: ONE QUERY per block, grid 2048, 256 threads, ~15KB LDS.
// attention -> LN2 -> FFN -> mask, then (L0) LN1+QKV(L1) via W^T L2 gemvs,
// (L1) LNf+logits.
__global__ __launch_bounds__(256,6) void k_attn1(KArgs a, int layer){
    __shared__ __align__(16) char smem[14912];
    float* sQ  =(float*)smem;             // [128]        0..512
    float* sS  =(float*)(smem+512);       // [4][256]     512..4608
    us16*  sTM =(us16*)(smem+4608);       // [256]        4608..5120
    float* sPr =(float*)(smem+5120);      // [16][128]    5120..13312
    float* sRed=(float*)(smem+13312);     // 4
    float* sRed2=(float*)(smem+13328);    // 4
    float* sX  =(float*)(smem+13344);     // [128]
    float* sH  =(float*)(smem+13856);     // [128]
    float* sY  =(float*)(smem+14368);     // [128]
    float* sRB =(float*)(smem+14880);     // 8

    int tid=threadIdx.x, bid=blockIdx.x;
    int b=bid&7, j=bid>>3;
    int q = (j&1)? (255-(j>>1)) : (j>>1);   // alternate small/large for balance
    int b0=b*L_, r=b0+q;
    bool pad=a.log_seqs[r]==0;
    const us16* Qb = layer? a.Qb1:a.Qb0;
    const us16* Kb = layer? a.Kb1:a.Kb0;
    const us16* Vb = layer? a.Vb1:a.Vb0;
    const float* qin = layer? a.qin1:a.qin0;
    const float scale=0.17677669529663687f;   // 1/sqrt(32)
    if(tid<128) sQ[tid]=us2f(Qb[(size_t)r*128+tid])*scale;
    int k=tid;
    int tm=a.tmat[(size_t)r*L_+k];
    sTM[k]=(us16)tm;
    __syncthreads();

    // phase 1: scores = Qs.(K' + timeK[tm]); causal-skip loads
    {
        bool act=(k<=q)&&!pad;
        float acc[4]={0.f,0.f,0.f,0.f};
        if(act){
            const uint4* K4=(const uint4*)(Kb+(size_t)(b0+k)*128);
            const uint4* T4=(const uint4*)(a.tmK+(size_t)tm*128);
            const float4* Q4=(const float4*)sQ;
            #pragma unroll 4
            for(int c=0;c<16;c++){
                uint4 kv=K4[c]; uint4 tv=T4[c];
                float4 qa=Q4[2*c], qb=Q4[2*c+1];
                const us16* ku=(const us16*)&kv;
                const us16* tu=(const us16*)&tv;
                acc[c>>2]+= qa.x*(us2f(ku[0])+us2f(tu[0]))
                          + qa.y*(us2f(ku[1])+us2f(tu[1]))
                          + qa.z*(us2f(ku[2])+us2f(tu[2]))
                          + qa.w*(us2f(ku[3])+us2f(tu[3]))
                          + qb.x*(us2f(ku[4])+us2f(tu[4]))
                          + qb.y*(us2f(ku[5])+us2f(tu[5]))
                          + qb.z*(us2f(ku[6])+us2f(tu[6]))
                          + qb.w*(us2f(ku[7])+us2f(tu[7]));
            }
        }
        #pragma unroll
        for(int h=0;h<H_;h++) sS[h*256+k]= act? acc[h]:NEGV;
    }
    __syncthreads();

    // phase 2: softmax; wave h -> head h
    {
        int h=tid>>6, lane=tid&63;
        float* row=sS+h*256;
        float v0=row[lane],v1=row[lane+64],v2=row[lane+128],v3=row[lane+192];
        float mm=fmaxf(fmaxf(v0,v1),fmaxf(v2,v3));
        #pragma unroll
        for(int o=32;o;o>>=1) mm=fmaxf(mm,__shfl_xor(mm,o,64));
        float e0=__expf(v0-mm),e1=__expf(v1-mm),e2=__expf(v2-mm),e3=__expf(v3-mm);
        float ss=e0+e1+e2+e3;
        #pragma unroll
        for(int o=32;o;o>>=1) ss+=__shfl_xor(ss,o,64);
        float inv=1.f/ss;
        row[lane]=e0*inv; row[lane+64]=e1*inv; row[lane+128]=e2*inv; row[lane+192]=e3*inv;
    }
    __syncthreads();

    // phase 3: A @ (V'+timeV[tm]); thread = (kslice 0..15, dq 0..15), 16B loads
    {
        int s16=tid>>4, dq=tid&15, hh=dq>>2;
        int kend=pad?L_:q+1;
        int k0=s16*16;
        int kmax=kend-k0; kmax=kmax<0?0:(kmax>16?16:kmax);
        const float* row=sS+hh*256;
        float a0=0,a1=0,a2=0,a3=0,a4=0,a5=0,a6=0,a7=0;
        for(int kk=0;kk<kmax;kk++){
            int kx=k0+kk;
            float aa=row[kx];
            int tmk=sTM[kx];
            uint4 v4=((const uint4*)(Vb+(size_t)(b0+kx)*128))[dq];
            uint4 t4=((const uint4*)(a.tmV+(size_t)tmk*128))[dq];
            const us16* vu=(const us16*)&v4;
            const us16* tu=(const us16*)&t4;
            a0=fmaf(aa,us2f(vu[0])+us2f(tu[0]),a0);
            a1=fmaf(aa,us2f(vu[1])+us2f(tu[1]),a1);
            a2=fmaf(aa,us2f(vu[2])+us2f(tu[2]),a2);
            a3=fmaf(aa,us2f(vu[3])+us2f(tu[3]),a3);
            a4=fmaf(aa,us2f(vu[4])+us2f(tu[4]),a4);
            a5=fmaf(aa,us2f(vu[5])+us2f(tu[5]),a5);
            a6=fmaf(aa,us2f(vu[6])+us2f(tu[6]),a6);
            a7=fmaf(aa,us2f(vu[7])+us2f(tu[7]),a7);
        }
        float* dst=sPr+s16*128+dq*8;
        ((float4*)dst)[0]=make_float4(a0,a1,a2,a3);
        ((float4*)dst)[1]=make_float4(a4,a5,a6,a7);
    }
    __syncthreads();

    // epilogue: +qin residual, LN2 -> sX. Uniform barriers (upper half contributes 0).
    int l=tid&127, half=tid>>7;
    float v=0.f;
    if(half==0){
        v=qin[(size_t)r*128+l];
        #pragma unroll
        for(int sl=0;sl<16;sl++) v+=sPr[sl*128+l];
    }
    {
        float s = half? 0.f : v;
        #pragma unroll
        for(int o=32;o;o>>=1) s+=__shfl_xor(s,o,64);
        if((tid&63)==0) sRed[tid>>6]=s;
        __syncthreads();
        float m=(sRed[0]+sRed[1])*(1.f/128.f);
        float d=v-m;
        float vv= half? 0.f : d*d;
        #pragma unroll
        for(int o=32;o;o>>=1) vv+=__shfl_xor(vv,o,64);
        if((tid&63)==0) sRed2[tid>>6]=vv;
        __syncthreads();
        float rstd=rsqrtf((sRed2[0]+sRed2[1])*(1.f/128.f)+1e-8f);
        if(half==0) sX[l]=d*rstd*a.ln2g[layer*128+l]+a.ln2b[layer*128+l];
    }
    __syncthreads();

    // FFN via W^T direct-from-L2 gemvs; threads 0..127 compute, barriers uniform.
    int cc=l;
    const us16* WT1 = a.wsWT + (size_t)(layer?5:0)*16384;
    const us16* WT2 = a.wsWT + (size_t)(layer?6:1)*16384;
    if(half==0){
        float h1=gemv_wt(WT1+(size_t)cc*128, sX);
        sH[cc]=fmaxf(h1+a.b1[layer*128+cc],0.f);
    }
    __syncthreads();
    float f=0.f;
    if(half==0){
        f=gemv_wt(WT2+(size_t)cc*128, sH)+a.b2[layer*128+cc]+sX[cc];
        if(pad) f=0.f;
        sY[cc]=f;
    }
    __syncthreads();

    if(layer==0){
        // LN1(L1) on f -> qin1 + sX; raw f in sY for K,V
        float s2 = half? 0.f : f;
        #pragma unroll
        for(int o=32;o;o>>=1) s2+=__shfl_xor(s2,o,64);
        if((tid&63)==0) sRB[tid>>6]=s2;
        __syncthreads();
        float m1=(sRB[0]+sRB[1])*(1.f/128.f);
        float d1=f-m1;
        float vv1= half? 0.f : d1*d1;
        #pragma unroll
        for(int o=32;o;o>>=1) vv1+=__shfl_xor(vv1,o,64);
        if((tid&63)==0) sRB[4+(tid>>6)]=vv1;
        __syncthreads();
        float rstd1=rsqrtf((sRB[4]+sRB[5])*(1.f/128.f)+1e-8f);
        if(half==0){
            float y1=d1*rstd1*a.ln1g[128+cc]+a.ln1b[128+cc];
            a.qin1[(size_t)r*128+cc]=y1;
            sX[cc]=y1;
        }
        __syncthreads();
        if(half==0){
            float Qv=gemv_wt(a.wsWT+(size_t)2*16384+(size_t)cc*128, sX)+a.bq[128+cc];
            a.Qb1[(size_t)r*128+cc]=f2us(Qv);
            float Kv=gemv_wt(a.wsWT+(size_t)3*16384+(size_t)cc*128, sY)
                     +a.bk[128+cc]+a.posK[q*128+cc];
            a.Kb1[(size_t)r*128+cc]=f2us(Kv);
            float Vv=gemv_wt(a.wsWT+(size_t)4*16384+(size_t)cc*128, sY)
                     +a.bv[128+cc]+a.posV[q*128+cc];
            a.Vb1[(size_t)r*128+cc]=f2us(Vv);
        }
    } else {
        // LNf + logits
        float s2 = half? 0.f : f;
        #pragma unroll
        for(int o=32;o;o>>=1) s2+=__shfl_xor(s2,o,64);
        if((tid&63)==0) sRB[tid>>6]=s2;
        __syncthreads();
        float m1=(sRB[0]+sRB[1])*(1.f/128.f);
        float d1=f-m1;
        float vv1= half? 0.f : d1*d1;
        #pragma unroll
        for(int o=32;o;o>>=1) vv1+=__shfl_xor(vv1,o,64);
        if((tid&63)==0) sRB[4+(tid>>6)]=vv1;
        __syncthreads();
        float rstd1=rsqrtf((sRB[4]+sRB[5])*(1.f/128.f)+1e-8f);
        if(half==0) sX[cc]=d1*rstd1*a.lnfg[cc]+a.lnfb[cc];
        __syncthreads();
        int w=tid>>6, lane=tid&63;
        if(w<2){
            int neg=w;
            int id = neg? a.neg_seqs[r] : a.pos_seqs[r];
            const float* e=a.item_emb+(size_t)id*128;
            float sdot = sX[lane]*e[lane] + sX[lane+64]*e[lane+64];
            #pragma unroll
            for(int o=32;o;o>>=1) sdot+=__shfl_xor(sdot,o,64);
            if(lane==0) a.out[neg*ROWS+r]=sdot;
        }
    }
}

extern "C" void kernel_launch(void* const* d_in, const int* in_sizes, int n_in,
                              void* d_out, int out_size, void* d_ws, size_t ws_size,
                              hipStream_t stream) {
    KArgs a;
    a.log_seqs=(const int*)d_in[1];
    a.tmat    =(const int*)d_in[2];
    a.pos_seqs=(const int*)d_in[3];
    a.neg_seqs=(const int*)d_in[4];
    a.item_emb=(const float*)d_in[5];
    a.posK =(const float*)d_in[6];
    a.posV =(const float*)d_in[7];
    a.timeK=(const float*)d_in[8];
    a.timeV=(const float*)d_in[9];
    a.ln1g=(const float*)d_in[10];
    a.ln1b=(const float*)d_in[11];
    a.Wq=(const float*)d_in[12];
    a.bq=(const float*)d_in[13];
    a.Wk=(const float*)d_in[14];
    a.bk=(const float*)d_in[15];
    a.Wv=(const float*)d_in[16];
    a.bv=(const float*)d_in[17];
    a.ln2g=(const float*)d_in[18];
    a.ln2b=(const float*)d_in[19];
    a.W1=(const float*)d_in[20];
    a.b1=(const float*)d_in[21];
    a.W2=(const float*)d_in[22];
    a.b2=(const float*)d_in[23];
    a.lnfg=(const float*)d_in[24];
    a.lnfb=(const float*)d_in[25];

    const size_t MB=1u<<20;
    char* w=(char*)d_ws;
    a.qin0=(float*)(w+0*MB);
    a.qin1=(float*)(w+1*MB);
    a.Qb0 =(us16*) (w+2*MB);
    a.Kb0 =(us16*) (w+2*MB+512*1024);
    a.Vb0 =(us16*) (w+3*MB);
    a.Qb1 =(us16*) (w+3*MB+512*1024);
    a.Kb1 =(us16*) (w+4*MB);
    a.Vb1 =(us16*) (w+4*MB+512*1024);
    a.wsWT=(us16*) (w+5*MB);              // 7 x 32KB transposed
    a.tmK =(us16*) (w+5*MB+256*1024);     // 65792 B
    a.tmV =(us16*) (w+5*MB+384*1024);
    a.out =(float*)d_out;

    k_pre<<<946,256,0,stream>>>(a);
    k_attn1<<<2048,256,0,stream>>>(a,0);
    k_attn1<<<2048,256,0,stream>>>(a,1);
}

// Round 14
// 243.962 us; speedup vs baseline: 1.1137x; 1.1137x over previous
//
#include <hip/hip_runtime.h>
#include <hip/hip_bf16.h>

#define L_ 256
#define H_ 4
#define ROWS 2048
#define NEGV (-4294967295.0f)   // -(2^32)+1 as float

typedef unsigned short us16;

__device__ __forceinline__ float us2f(us16 u){ return __uint_as_float(((unsigned)u)<<16); }
__device__ __forceinline__ us16 f2us(float f){ __hip_bfloat16 h=__float2bfloat16(f); return *(us16*)&h; }

struct KArgs {
    const int *log_seqs, *tmat, *pos_seqs, *neg_seqs;
    const float *item_emb, *posK, *posV, *timeK, *timeV;
    const float *ln1g, *ln1b, *bq, *bk, *bv, *ln2g, *ln2b, *b1, *b2, *lnfg, *lnfb;
    const float *Wq, *Wk, *Wv, *W1, *W2;
    float *qin0, *qin1, *seqs1, *PVp, *MSp, *out;
    us16 *wsW, *tmK, *tmV, *Qb0, *Kb0, *Vb0, *Qb1, *Kb1, *Vb1;
};

// LayerNorm of 8 LDS rows in place; thread t: row t>>5, 4 elems strided 32.
__device__ __forceinline__ void ln_rows(float* sA,
        const float* __restrict__ g, const float* __restrict__ b,
        float* qin_out, int r0, int tid){
    int r=tid>>5, l=tid&31;
    float* x=sA+r*128;
    float x0=x[l],x1=x[l+32],x2=x[l+64],x3=x[l+96];
    float s=x0+x1+x2+x3;
    #pragma unroll
    for(int o=16;o;o>>=1) s+=__shfl_xor(s,o,64);
    float m=s*(1.f/128.f);
    float d0=x0-m,d1=x1-m,d2=x2-m,d3=x3-m;
    float v=d0*d0+d1*d1+d2*d2+d3*d3;
    #pragma unroll
    for(int o=16;o;o>>=1) v+=__shfl_xor(v,o,64);
    float rstd=rsqrtf(v*(1.f/128.f)+1e-8f);
    float y0=d0*rstd*g[l]+b[l];
    float y1=d1*rstd*g[l+32]+b[l+32];
    float y2=d2*rstd*g[l+64]+b[l+64];
    float y3=d3*rstd*g[l+96]+b[l+96];
    x[l]=y0; x[l+32]=y1; x[l+64]=y2; x[l+96]=y3;
    if(qin_out){
        float* q=qin_out+(size_t)(r0+r)*128;
        q[l]=y0; q[l+32]=y1; q[l+64]=y2; q[l+96]=y3;
    }
}

__device__ __forceinline__ void gemm2x2(const float* A, const us16* sW,
        int ra, int rb, int c0, float* acc){
    float a00=0,a01=0,a10=0,a11=0;
    const float* Ar=A+ra*128;
    const float* Br=A+rb*128;
    #pragma unroll 8
    for(int k=0;k<128;k++){
        ushort2 wp=*(const ushort2*)(sW+k*128+c0);
        float w0=us2f(wp.x), w1=us2f(wp.y);
        float x0=Ar[k], x1=Br[k];
        a00=fmaf(x0,w0,a00); a01=fmaf(x0,w1,a01);
        a10=fmaf(x1,w0,a10); a11=fmaf(x1,w1,a11);
    }
    acc[0]=a00; acc[1]=a01; acc[2]=a10; acc[3]=a11;
}

__device__ __forceinline__ void gemm1x2(const float* Ar, const us16* sW,
        int c0, float& o0, float& o1){
    float a0=0,a1=0;
    #pragma unroll 8
    for(int k=0;k<128;k++){
        ushort2 wp=*(const ushort2*)(sW+k*128+c0);
        float x=Ar[k];
        a0=fmaf(x,us2f(wp.x),a0);
        a1=fmaf(x,us2f(wp.y),a1);
    }
    o0=a0; o1=a1;
}

// stage 128x128 bf16 matrix (32KB) global -> LDS: 8 uint4/thread (256 thr)
__device__ __forceinline__ void stage_w(const us16* __restrict__ Wg, us16* sW, int tid){
    const uint4* src=(const uint4*)Wg;
    uint4* dst=(uint4*)sW;
    #pragma unroll
    for(int j=0;j<8;j++) dst[j*256+tid]=src[j*256+tid];
}

// k_pre: bid<768: embed+LN1+QKV(L0) (8 rows/block, fp32 weights staged->bf16 LDS).
//        bid 768..879: convert 7 tail matrices fp32 -> bf16 wsW (k-major).
//        bid 880..945: convert timeK/timeV tables to bf16.
__global__ __launch_bounds__(256) void k_pre(KArgs a){
    __shared__ __align__(16) char smem[36864];
    int tid=threadIdx.x, bid=blockIdx.x;
    if(bid<768){
        us16* sW=(us16*)smem;
        float* sA=(float*)(smem+32768);
        int m=bid>>8, rg=bid&255, r0=rg*8;
        {   // embed 8 rows
            int rl=tid>>5, c4=tid&31;
            int id=a.log_seqs[r0+rl];
            float4 v=((const float4*)a.item_emb)[id*32+c4];
            float sc = id? 11.3137085f : 0.f;   // sqrt(128), pad-zeroed
            v.x*=sc; v.y*=sc; v.z*=sc; v.w*=sc;
            ((float4*)sA)[tid]=v;
        }
        const float* Wsrc=(m==0)?a.Wq:(m==1)?a.Wk:a.Wv;
        {   // stage fp32 weights -> bf16 LDS
            const float4* src=(const float4*)Wsrc;
            ushort4* dst=(ushort4*)sW;
            #pragma unroll
            for(int j=0;j<16;j++){
                float4 w=src[j*256+tid];
                ushort4 o; o.x=f2us(w.x);o.y=f2us(w.y);o.z=f2us(w.z);o.w=f2us(w.w);
                dst[j*256+tid]=o;
            }
        }
        __syncthreads();
        if(m==0){ ln_rows(sA, a.ln1g, a.ln1b, a.qin0, r0, tid); __syncthreads(); }
        int cp=tid&63, rp=tid>>6, c0=2*cp, ra=2*rp, rb=ra+1;
        float acc[4];
        gemm2x2(sA,sW,ra,rb,c0,acc);
        if(m==0){
            float b0v=a.bq[c0], b1v=a.bq[c0+1];
            ushort2 s0; s0.x=f2us(acc[0]+b0v); s0.y=f2us(acc[1]+b1v);
            ushort2 s1; s1.x=f2us(acc[2]+b0v); s1.y=f2us(acc[3]+b1v);
            *(ushort2*)(a.Qb0+(size_t)(r0+ra)*128+c0)=s0;
            *(ushort2*)(a.Qb0+(size_t)(r0+rb)*128+c0)=s1;
        } else {
            const float* bb=(m==1)?a.bk:a.bv;
            const float* pp=(m==1)?a.posK:a.posV;
            us16* Oo=(m==1)?a.Kb0:a.Vb0;
            int qa=(r0+ra)&255, qb2=(r0+rb)&255;
            float b0v=bb[c0], b1v=bb[c0+1];
            ushort2 s0; s0.x=f2us(acc[0]+b0v+pp[qa*128+c0]);  s0.y=f2us(acc[1]+b1v+pp[qa*128+c0+1]);
            ushort2 s1; s1.x=f2us(acc[2]+b0v+pp[qb2*128+c0]); s1.y=f2us(acc[3]+b1v+pp[qb2*128+c0+1]);
            *(ushort2*)(Oo+(size_t)(r0+ra)*128+c0)=s0;
            *(ushort2*)(Oo+(size_t)(r0+rb)*128+c0)=s1;
        }
    } else if(bid<880){
        int j=bid-768; int m=j>>4; int idx=(j&15)*256+tid;   // float4 idx
        const float* base;
        switch(m){
            case 0: base=a.W1; break;        case 1: base=a.W2; break;
            case 2: base=a.Wq+16384; break;  case 3: base=a.Wk+16384; break;
            case 4: base=a.Wv+16384; break;  case 5: base=a.W1+16384; break;
            default: base=a.W2+16384; break;
        }
        float4 v=((const float4*)base)[idx];
        ushort4 o; o.x=f2us(v.x);o.y=f2us(v.y);o.z=f2us(v.z);o.w=f2us(v.w);
        ((ushort4*)(a.wsW+(size_t)m*16384))[idx]=o;
    } else {
        int gi=(bid-880)*256+tid;     // 2 x 8224 float4
        if(gi<8224){
            float4 v=((const float4*)a.timeK)[gi];
            ushort4 o; o.x=f2us(v.x);o.y=f2us(v.y);o.z=f2us(v.z);o.w=f2us(v.w);
            ((ushort4*)a.tmK)[gi]=o;
        } else if(gi<16448){
            int g2=gi-8224;
            float4 v=((const float4*)a.timeV)[g2];
            ushort4 o; o.x=f2us(v.x);o.y=f2us(v.y);o.z=f2us(v.z);o.w=f2us(v.w);
            ((ushort4*)a.tmV)[g2]=o;
        }
    }
}

// k_attnp: partial attention. grid 2048 = (b<<8)|(kh<<7)|qp. 256 thr, ~14KB LDS.
// Queries {qp, 255-qp}; keys [kh*128, kh*128+128). Writes unnormalized PV + (m,s).
__global__ __launch_bounds__(256,8) void k_attnp(KArgs a, int layer){
    __shared__ __align__(16) char smem[14080];
    float* sQ  =(float*)smem;             // [2][128]   0..1024
    float* sS  =(float*)(smem+1024);      // [8][128]   1024..5120  (i2*4+h)
    us16*  sTM =(us16*)(smem+5120);       // [2][128]   5120..5632
    float* sPr =(float*)(smem+5632);      // [16][128]  5632..13824
    float* sMS =(float*)(smem+13824);     // [16]       m,s per (i2*4+h)

    int tid=threadIdx.x, bid=blockIdx.x;
    int qp=bid&127, kh=(bid>>7)&1, b=bid>>8;
    int q1=qp, q2=255-qp, b0=b*L_;
    int r1=b0+q1, r2=b0+q2;
    int k0=kh*128;
    bool pad1=a.log_seqs[r1]==0, pad2=a.log_seqs[r2]==0;
    const us16* Qb = layer? a.Qb1:a.Qb0;
    const us16* Kb = layer? a.Kb1:a.Kb0;
    const us16* Vb = layer? a.Vb1:a.Vb0;
    const float scale=0.17677669529663687f;   // 1/sqrt(32)
    {
        int i2=tid>>7, l=tid&127;
        sQ[i2*128+l]=us2f(Qb[(size_t)(i2?r2:r1)*128+l])*scale;
    }
    int i2g=tid>>7, kk=tid&127, kg=k0+kk;
    int rgr = i2g? r2:r1;
    int tmg = a.tmat[(size_t)rgr*L_+kg];
    sTM[i2g*128+kk]=(us16)tmg;
    __syncthreads();

    // phase 1: scores = Qs.(K' + timeK[tm]) for own (query, key)
    {
        int qq = i2g? q2:q1; bool pad = i2g? pad2:pad1;
        bool act=(kg<=qq)&&!pad;
        float acc[4]={0.f,0.f,0.f,0.f};
        if(act){
            const uint4* K4=(const uint4*)(Kb+(size_t)(b0+kg)*128);
            const uint4* T4=(const uint4*)(a.tmK+(size_t)tmg*128);
            const float4* Q4=(const float4*)(sQ+i2g*128);
            #pragma unroll 4
            for(int c=0;c<16;c++){
                uint4 kv=K4[c]; uint4 tv=T4[c];
                float4 qa=Q4[2*c], qb=Q4[2*c+1];
                const us16* ku=(const us16*)&kv;
                const us16* tu=(const us16*)&tv;
                acc[c>>2]+= qa.x*(us2f(ku[0])+us2f(tu[0]))
                          + qa.y*(us2f(ku[1])+us2f(tu[1]))
                          + qa.z*(us2f(ku[2])+us2f(tu[2]))
                          + qa.w*(us2f(ku[3])+us2f(tu[3]))
                          + qb.x*(us2f(ku[4])+us2f(tu[4]))
                          + qb.y*(us2f(ku[5])+us2f(tu[5]))
                          + qb.z*(us2f(ku[6])+us2f(tu[6]))
                          + qb.w*(us2f(ku[7])+us2f(tu[7]));
            }
        }
        #pragma unroll
        for(int h=0;h<H_;h++) sS[(i2g*4+h)*128+kk]= act? acc[h]:NEGV;
    }
    __syncthreads();

    // phase 2: PARTIAL softmax per row: m=max, p=exp(x-m) (unnormalized), s=sum p
    {
        int w=tid>>6, lane=tid&63;
        #pragma unroll
        for(int rr=0;rr<2;rr++){
            int row=w*2+rr;
            float* rp_=sS+row*128;
            float v0=rp_[lane], v1=rp_[lane+64];
            float mm=fmaxf(v0,v1);
            #pragma unroll
            for(int o=32;o;o>>=1) mm=fmaxf(mm,__shfl_xor(mm,o,64));
            float e0=__expf(v0-mm), e1=__expf(v1-mm);
            float ss=e0+e1;
            #pragma unroll
            for(int o=32;o;o>>=1) ss+=__shfl_xor(ss,o,64);
            rp_[lane]=e0; rp_[lane+64]=e1;
            if(lane==0){ sMS[row*2]=mm; sMS[row*2+1]=ss; }
        }
    }
    __syncthreads();

    // phase 3: PV_partial = p @ (V' + timeV[tm]) over own 128-key range
    {
        int i2=tid>>7, s8=(tid>>4)&7, dq=tid&15, hh=dq>>2;
        int qq=i2?q2:q1; bool pad=i2?pad2:pad1;
        int kendg = pad? L_ : qq+1;
        int kend = kendg - k0; kend = kend<0?0:(kend>128?128:kend);
        int kk0=s8*16;
        int kmax=kend-kk0; kmax=kmax<0?0:(kmax>16?16:kmax);
        const float* row=sS+(i2*4+hh)*128;
        const us16* tmrow=sTM+i2*128;
        float a0=0,a1=0,a2=0,a3=0,a4=0,a5=0,a6=0,a7=0;
        for(int kq=0;kq<kmax;kq++){
            int kx=kk0+kq;
            float aa=row[kx];
            int tmk=tmrow[kx];
            uint4 v4=((const uint4*)(Vb+(size_t)(b0+k0+kx)*128))[dq];
            uint4 t4=((const uint4*)(a.tmV+(size_t)tmk*128))[dq];
            const us16* vu=(const us16*)&v4;
            const us16* tu=(const us16*)&t4;
            a0=fmaf(aa,us2f(vu[0])+us2f(tu[0]),a0);
            a1=fmaf(aa,us2f(vu[1])+us2f(tu[1]),a1);
            a2=fmaf(aa,us2f(vu[2])+us2f(tu[2]),a2);
            a3=fmaf(aa,us2f(vu[3])+us2f(tu[3]),a3);
            a4=fmaf(aa,us2f(vu[4])+us2f(tu[4]),a4);
            a5=fmaf(aa,us2f(vu[5])+us2f(tu[5]),a5);
            a6=fmaf(aa,us2f(vu[6])+us2f(tu[6]),a6);
            a7=fmaf(aa,us2f(vu[7])+us2f(tu[7]),a7);
        }
        float* dst=sPr+(i2*8+s8)*128+dq*8;
        ((float4*)dst)[0]=make_float4(a0,a1,a2,a3);
        ((float4*)dst)[1]=make_float4(a4,a5,a6,a7);
    }
    __syncthreads();

    // reduce slices, write partials
    {
        int i2=tid>>7, l=tid&127;
        float pv=0;
        #pragma unroll
        for(int s=0;s<8;s++) pv+=sPr[(i2*8+s)*128+l];
        a.PVp[(size_t)bid*256 + i2*128 + l]=pv;
        if(tid<16) a.MSp[(size_t)bid*16+tid]=sMS[tid];
    }
}

// k_qkv: layer-1 QKV. grid 768 = {Q,K,V} x 256 rowgroups of 8 (reads seqs1).
__global__ __launch_bounds__(256) void k_qkv(KArgs a){
    __shared__ __align__(16) char smem[36864];
    us16* sW=(us16*)smem;
    float* sA=(float*)(smem+32768);
    int tid=threadIdx.x;
    int m=blockIdx.x>>8, rg=blockIdx.x&255, r0=rg*8;
    ((float4*)sA)[tid]=((const float4*)(a.seqs1+(size_t)r0*128))[tid];
    stage_w(a.wsW+(size_t)(2+m)*16384, sW, tid);
    __syncthreads();
    if(m==0){ ln_rows(sA, a.ln1g+128, a.ln1b+128, a.qin1, r0, tid); __syncthreads(); }
    int cp=tid&63, rp=tid>>6, c0=2*cp, ra=2*rp, rb=ra+1;
    float acc[4];
    gemm2x2(sA,sW,ra,rb,c0,acc);
    if(m==0){
        float b0v=a.bq[128+c0], b1v=a.bq[128+c0+1];
        ushort2 s0; s0.x=f2us(acc[0]+b0v); s0.y=f2us(acc[1]+b1v);
        ushort2 s1; s1.x=f2us(acc[2]+b0v); s1.y=f2us(acc[3]+b1v);
        *(ushort2*)(a.Qb1+(size_t)(r0+ra)*128+c0)=s0;
        *(ushort2*)(a.Qb1+(size_t)(r0+rb)*128+c0)=s1;
    } else {
        const float* bb=(m==1)?(a.bk+128):(a.bv+128);
        const float* pp=(m==1)?a.posK:a.posV;
        us16* Oo=(m==1)?a.Kb1:a.Vb1;
        int qa=(r0+ra)&255, qb2=(r0+rb)&255;
        float b0v=bb[c0], b1v=bb[c0+1];
        ushort2 s0; s0.x=f2us(acc[0]+b0v+pp[qa*128+c0]);  s0.y=f2us(acc[1]+b1v+pp[qa*128+c0+1]);
        ushort2 s1; s1.x=f2us(acc[2]+b0v+pp[qb2*128+c0]); s1.y=f2us(acc[3]+b1v+pp[qb2*128+c0+1]);
        *(ushort2*)(Oo+(size_t)(r0+ra)*128+c0)=s0;
        *(ushort2*)(Oo+(size_t)(r0+rb)*128+c0)=s1;
    }
}

// k_cffn: combine partials + LN2 + FFN. grid 512 x 4 rows (row per wave).
// final_=0: write seqs1.  final_=1: LNf + pos/neg logits -> out.
__global__ __launch_bounds__(256) void k_cffn(KArgs a, int layer, int final_,
                                              int slotW1, int slotW2){
    __shared__ __align__(16) char smem[36864];
    us16* sW=(us16*)smem;
    float* sA=(float*)(smem+32768);   // [4][128] LN2 output x
    float* sH=(float*)(smem+34816);   // [4][128] hidden
    int tid=threadIdx.x;
    int r0=blockIdx.x*4;
    int rp=tid>>6, lane=tid&63;
    int r=r0+rp;
    int b=r>>8, q=r&255;
    int i2=(q>=128)?1:0;
    int qp=i2? 255-q : q;
    const float* qin = layer? a.qin1:a.qin0;
    bool pad = a.log_seqs[r]==0;
    size_t blk0=(size_t)(b*256+qp), blk1=(size_t)(b*256+128+qp);
    stage_w(a.wsW+(size_t)slotW1*16384, sW, tid);

    // combine: 2 dims per thread (lane, lane+64)
    float o0,o1;
    {
        int d=lane; int h=d>>5;
        float m0=a.MSp[blk0*16+(i2*4+h)*2],   s0=a.MSp[blk0*16+(i2*4+h)*2+1];
        float m1=a.MSp[blk1*16+(i2*4+h)*2],   s1=a.MSp[blk1*16+(i2*4+h)*2+1];
        float M=fmaxf(m0,m1);
        float w0=__expf(m0-M), w1=__expf(m1-M);
        float pv=w0*a.PVp[blk0*256+i2*128+d]+w1*a.PVp[blk1*256+i2*128+d];
        o0=pv/(w0*s0+w1*s1)+qin[(size_t)r*128+d];
    }
    {
        int d=lane+64; int h=d>>5;
        float m0=a.MSp[blk0*16+(i2*4+h)*2],   s0=a.MSp[blk0*16+(i2*4+h)*2+1];
        float m1=a.MSp[blk1*16+(i2*4+h)*2],   s1=a.MSp[blk1*16+(i2*4+h)*2+1];
        float M=fmaxf(m0,m1);
        float w0=__expf(m0-M), w1=__expf(m1-M);
        float pv=w0*a.PVp[blk0*256+i2*128+d]+w1*a.PVp[blk1*256+i2*128+d];
        o1=pv/(w0*s0+w1*s1)+qin[(size_t)r*128+d];
    }
    // LN2 (row per wave)
    {
        float s=o0+o1;
        #pragma unroll
        for(int o=32;o;o>>=1) s+=__shfl_xor(s,o,64);
        float m=s*(1.f/128.f);
        float d0=o0-m, d1=o1-m;
        float v=d0*d0+d1*d1;
        #pragma unroll
        for(int o=32;o;o>>=1) v+=__shfl_xor(v,o,64);
        float rstd=rsqrtf(v*(1.f/128.f)+1e-8f);
        sA[rp*128+lane]   =d0*rstd*a.ln2g[layer*128+lane]+a.ln2b[layer*128+lane];
        sA[rp*128+lane+64]=d1*rstd*a.ln2g[layer*128+lane+64]+a.ln2b[layer*128+lane+64];
    }
    __syncthreads();
    int c0=2*lane;
    float h0,h1;
    gemm1x2(sA+rp*128, sW, c0, h0, h1);
    sH[rp*128+c0]  =fmaxf(h0+a.b1[layer*128+c0],0.f);
    sH[rp*128+c0+1]=fmaxf(h1+a.b1[layer*128+c0+1],0.f);
    __syncthreads();
    stage_w(a.wsW+(size_t)slotW2*16384, sW, tid);
    __syncthreads();
    float f0,f1;
    gemm1x2(sH+rp*128, sW, c0, f0, f1);
    f0 = pad?0.f:(f0+a.b2[layer*128+c0]  +sA[rp*128+c0]);
    f1 = pad?0.f:(f1+a.b2[layer*128+c0+1]+sA[rp*128+c0+1]);
    if(!final_){
        a.seqs1[(size_t)r*128+c0]=f0;
        a.seqs1[(size_t)r*128+c0+1]=f1;
    } else {
        __syncthreads();                   // all gemv reads of sA done
        sA[rp*128+c0]=f0; sA[rp*128+c0+1]=f1;
        __syncthreads();
        // LNf (row per wave; re-read this row's 2 strided elems)
        float x0=sA[rp*128+lane], x1=sA[rp*128+lane+64];
        float s=x0+x1;
        #pragma unroll
        for(int o=32;o;o>>=1) s+=__shfl_xor(s,o,64);
        float m=s*(1.f/128.f);
        float d0=x0-m, d1=x1-m;
        float v=d0*d0+d1*d1;
        #pragma unroll
        for(int o=32;o;o>>=1) v+=__shfl_xor(v,o,64);
        float rstd=rsqrtf(v*(1.f/128.f)+1e-8f);
        float y0=d0*rstd*a.lnfg[lane]+a.lnfb[lane];
        float y1=d1*rstd*a.lnfg[lane+64]+a.lnfb[lane+64];
        sH[rp*128+lane]=y0; sH[rp*128+lane+64]=y1;
        // logits (same wave wrote this row; in-wave LDS ordering suffices)
        #pragma unroll
        for(int neg=0;neg<2;neg++){
            int id = neg? a.neg_seqs[r] : a.pos_seqs[r];
            const float* e=a.item_emb+(size_t)id*128;
            float sd = sH[rp*128+lane]*e[lane] + sH[rp*128+lane+64]*e[lane+64];
            #pragma unroll
            for(int o=32;o;o>>=1) sd+=__shfl_xor(sd,o,64);
            if(lane==0) a.out[neg*ROWS+r]=sd;
        }
    }
}

extern "C" void kernel_launch(void* const* d_in, const int* in_sizes, int n_in,
                              void* d_out, int out_size, void* d_ws, size_t ws_size,
                              hipStream_t stream) {
    KArgs a;
    a.log_seqs=(const int*)d_in[1];
    a.tmat    =(const int*)d_in[2];
    a.pos_seqs=(const int*)d_in[3];
    a.neg_seqs=(const int*)d_in[4];
    a.item_emb=(const float*)d_in[5];
    a.posK =(const float*)d_in[6];
    a.posV =(const float*)d_in[7];
    a.timeK=(const float*)d_in[8];
    a.timeV=(const float*)d_in[9];
    a.ln1g=(const float*)d_in[10];
    a.ln1b=(const float*)d_in[11];
    a.Wq=(const float*)d_in[12];
    a.bq=(const float*)d_in[13];
    a.Wk=(const float*)d_in[14];
    a.bk=(const float*)d_in[15];
    a.Wv=(const float*)d_in[16];
    a.bv=(const float*)d_in[17];
    a.ln2g=(const float*)d_in[18];
    a.ln2b=(const float*)d_in[19];
    a.W1=(const float*)d_in[20];
    a.b1=(const float*)d_in[21];
    a.W2=(const float*)d_in[22];
    a.b2=(const float*)d_in[23];
    a.lnfg=(const float*)d_in[24];
    a.lnfb=(const float*)d_in[25];

    const size_t MB=1u<<20;
    char* w=(char*)d_ws;
    a.qin0 =(float*)(w+0*MB);
    a.qin1 =(float*)(w+1*MB);
    a.Qb0  =(us16*) (w+2*MB);
    a.Kb0  =(us16*) (w+2*MB+512*1024);
    a.Vb0  =(us16*) (w+3*MB);
    a.Qb1  =(us16*) (w+3*MB+512*1024);
    a.Kb1  =(us16*) (w+4*MB);
    a.Vb1  =(us16*) (w+4*MB+512*1024);
    a.wsW  =(us16*) (w+5*MB);             // 7 x 32KB, k-major
    a.tmK  =(us16*) (w+5*MB+256*1024);    // 65792 B
    a.tmV  =(us16*) (w+5*MB+384*1024);
    a.PVp  =(float*)(w+6*MB);             // 2048 x 256 fp32 = 2MB
    a.MSp  =(float*)(w+8*MB+512*1024);    // 2048 x 16 fp32 = 128KB
    a.seqs1=(float*)(w+9*MB);             // 1MB
    a.out  =(float*)d_out;

    k_pre  <<<946 ,256,0,stream>>>(a);
    k_attnp<<<2048,256,0,stream>>>(a,0);
    k_cffn <<<512 ,256,0,stream>>>(a,0,0, 0,1);   // W1_0,W2_0 -> seqs1
    k_qkv  <<<768 ,256,0,stream>>>(a);            // LN1+QKV(L1) from seqs1
    k_attnp<<<2048,256,0,stream>>>(a,1);
    k_cffn <<<512 ,256,0,stream>>>(a,1,1, 5,6);   // W1_1,W2_1 -> LNf+logits
}